// Round 3
// baseline (500.891 us; speedup 1.0000x reference)
//
#include <hip/hip_runtime.h>
#include <stdint.h>

// Problem constants
#define DD  128     // latent dim
#define HH  132     // FCBlock hidden width
#define BB  65536   // batch
#define KKC 8       // num components
#define HP  144     // padded hidden (N-dim, 9 tiles of 16)
#define KP  160     // padded K-dim for hidden layers (5 steps of 32)

typedef short bf16x8 __attribute__((ext_vector_type(8)));
typedef short bf16x4 __attribute__((ext_vector_type(4)));
typedef float f32x4  __attribute__((ext_vector_type(4)));

__device__ __forceinline__ unsigned short f2b(float f){
  union{float f; unsigned u;} c; c.f = f;
  unsigned r = c.u + 0x7fffu + ((c.u >> 16) & 1u);   // RNE
  return (unsigned short)(r >> 16);
}

// ---------------- prep A: Wf = Wu @ Wm (fp32), bfv = K*(Wu@bm) + bu ----------------
__global__ void prepA(const float* __restrict__ Wm, const float* __restrict__ bm,
                      const float* __restrict__ Wu, const float* __restrict__ bu,
                      float* __restrict__ Wf, float* __restrict__ bfv){
  int idx = blockIdx.x * 256 + threadIdx.x;      // 64 blocks -> 16384 = 128*128
  int i = idx >> 7, j = idx & 127;
  float acc = 0.f;
  for(int d = 0; d < DD; ++d)
    acc += Wu[i*DD + d] * Wm[d*DD + j];
  Wf[idx] = acc;
  if(j == 0){
    float a = 0.f;
    for(int d = 0; d < DD; ++d) a += Wu[i*DD + d] * bm[d];
    bfv[i] = (float)KKC * a + bu[i];
  }
}

// ---------------- prep B: fused + padded bf16 weights into workspace ----------------
__global__ void prepB(const float* __restrict__ W0, const float* __restrict__ b0,
                      const float* __restrict__ W1, const float* __restrict__ b1,
                      const float* __restrict__ W2, const float* __restrict__ b2,
                      const float* __restrict__ W3, const float* __restrict__ b3,
                      const float* __restrict__ Wf, const float* __restrict__ bfv,
                      unsigned short* __restrict__ w0s_p, unsigned short* __restrict__ w0rp,
                      unsigned short* __restrict__ w1p,  unsigned short* __restrict__ w2p,
                      unsigned short* __restrict__ w3p,
                      float* __restrict__ b0p, float* __restrict__ b1p,
                      float* __restrict__ b2p, float* __restrict__ b3p){
  int idx = blockIdx.x * 256 + threadIdx.x;
  if(idx < HP*DD){                                  // w0s_p: signal half of W0, padded
    int n = idx >> 7, k = idx & 127;
    w0s_p[idx] = (n < HH) ? f2b(W0[n*(2*DD) + k]) : (unsigned short)0;
    return;
  }
  idx -= HP*DD;
  if(idx < HP*DD){                                  // w0rp = W0r @ Wf, padded
    int n = idx >> 7, k = idx & 127;
    float acc = 0.f;
    if(n < HH)
      for(int i = 0; i < DD; ++i)
        acc += W0[n*(2*DD) + DD + i] * Wf[i*DD + k];
    w0rp[idx] = (n < HH) ? f2b(acc) : (unsigned short)0;
    return;
  }
  idx -= HP*DD;
  if(idx < HP*KP){                                  // w1p padded
    int n = idx / KP, k = idx % KP;
    w1p[idx] = (n < HH && k < HH) ? f2b(W1[n*HH + k]) : (unsigned short)0;
    return;
  }
  idx -= HP*KP;
  if(idx < HP*KP){                                  // w2p padded
    int n = idx / KP, k = idx % KP;
    w2p[idx] = (n < HH && k < HH) ? f2b(W2[n*HH + k]) : (unsigned short)0;
    return;
  }
  idx -= HP*KP;
  if(idx < DD*KP){                                  // w3p padded (N=128 full, K pad)
    int n = idx / KP, k = idx % KP;
    w3p[idx] = (k < HH) ? f2b(W3[n*HH + k]) : (unsigned short)0;
    return;
  }
  idx -= DD*KP;
  if(idx < HP){                                     // b0p = b0 + W0r @ bfv, padded
    float acc = 0.f;
    if(idx < HH){
      acc = b0[idx];
      for(int i = 0; i < DD; ++i) acc += W0[idx*(2*DD) + DD + i] * bfv[i];
    }
    b0p[idx] = acc;
    return;
  }
  idx -= HP;
  if(idx < HP){ b1p[idx] = (idx < HH) ? b1[idx] : 0.f; return; }
  idx -= HP;
  if(idx < HP){ b2p[idx] = (idx < HH) ? b2[idx] : 0.f; return; }
  idx -= HP;
  if(idx < DD){ b3p[idx] = b3[idx]; return; }
}

// ---------------- K1: pure streaming component sum -> bf16 [B,D] ----------------
// 8192 blocks x 256 threads; each thread: 8 independent 16B loads, vector sum,
// one 8B bf16 store. Low VGPR -> 8 waves/SIMD for max memory-level parallelism.
__global__ __launch_bounds__(256, 8) void comp_sum(
    const float* __restrict__ comps, unsigned short* __restrict__ sumb){
  const size_t idx4 = ((size_t)blockIdx.x * 256 + threadIdx.x) * 4;
  f32x4 a = {0.f,0.f,0.f,0.f};
  #pragma unroll
  for(int k = 0; k < KKC; ++k){
    f32x4 v = *(const f32x4*)(comps + (size_t)k * BB * DD + idx4);
    a += v;
  }
  bf16x4 p;
  #pragma unroll
  for(int j = 0; j < 4; ++j) p[j] = (short)f2b(a[j]);
  *(bf16x4*)(sumb + idx4) = p;
}

// ---------------- K2: fused 4-layer MLP, 1 wave per 16 rows ----------------
// Grid = B/16 = 4096 blocks of 64 threads. No inter-wave coupling.
// MFMA 16x16x32 bf16 layouts:
//   A frag : lane holds A[m=lane&15][k = (lane>>4)*8 + j], j=0..7
//   B frag : lane holds B[k][n=lane&15] -> W[n][k..k+7] row-major 16B
//   C/D    : lane holds D[row = (lane>>4)*4 + r][col = lane&15]
__global__ __launch_bounds__(64, 4) void fused_mlp(
    const float* __restrict__ signal,
    const unsigned short* __restrict__ sumb,
    const unsigned short* __restrict__ w0s_p,
    const unsigned short* __restrict__ w0rp,
    const unsigned short* __restrict__ w1p,
    const unsigned short* __restrict__ w2p,
    const unsigned short* __restrict__ w3p,
    const float* __restrict__ b0p, const float* __restrict__ b1p,
    const float* __restrict__ b2p, const float* __restrict__ b3p,
    float* __restrict__ out)
{
  const int tid  = threadIdx.x;
  const int m    = tid & 15;
  const int quad = tid >> 4;
  const int rowBase = blockIdx.x * 16;
  const int arow = rowBase + m;

  // 16 x KP activation tile; stride 168 elts keeps ds_read_b128 conflicts minor
  __shared__ unsigned short act[16][168];

  // zero the K-pad columns [144,160)
  for(int t = tid; t < 16*16; t += 64){
    act[t >> 4][144 + (t & 15)] = 0;
  }

  // ---- A-fragments: sum (bf16, direct) and signal (fp32 -> bf16) ----
  bf16x8 sumf[4];
  #pragma unroll
  for(int ki = 0; ki < 4; ++ki)
    sumf[ki] = *(const bf16x8*)(sumb + (size_t)arow*DD + ki*32 + quad*8);

  bf16x8 sigf[4];
  {
    const float* srow = signal + (size_t)arow * DD;
    #pragma unroll
    for(int ki = 0; ki < 4; ++ki){
      f32x4 lo = *(const f32x4*)(srow + ki*32 + quad*8);
      f32x4 hi = *(const f32x4*)(srow + ki*32 + quad*8 + 4);
      bf16x8 p;
      #pragma unroll
      for(int j = 0; j < 4; ++j){ p[j] = (short)f2b(lo[j]); p[4+j] = (short)f2b(hi[j]); }
      sigf[ki] = p;
    }
  }
  __syncthreads();   // single-wave: cheap; orders pad-zero writes vs later reads

  // ---- layer 0: h0 = relu(sig @ W0s^T + sum @ W0rp^T + b0p)  [N=144, K=128+128]
  #pragma unroll
  for(int nt = 0; nt < 9; ++nt){
    f32x4 acc = {0.f,0.f,0.f,0.f};
    const unsigned short* wr1 = w0s_p + (size_t)(nt*16 + m)*DD + quad*8;
    const unsigned short* wr2 = w0rp  + (size_t)(nt*16 + m)*DD + quad*8;
    #pragma unroll
    for(int ki = 0; ki < 4; ++ki){
      bf16x8 wf = *(const bf16x8*)(wr1 + ki*32);
      acc = __builtin_amdgcn_mfma_f32_16x16x32_bf16(sigf[ki], wf, acc, 0, 0, 0);
    }
    #pragma unroll
    for(int ki = 0; ki < 4; ++ki){
      bf16x8 wf = *(const bf16x8*)(wr2 + ki*32);
      acc = __builtin_amdgcn_mfma_f32_16x16x32_bf16(sumf[ki], wf, acc, 0, 0, 0);
    }
    float bias = b0p[nt*16 + m];
    #pragma unroll
    for(int r = 0; r < 4; ++r){
      float v = acc[r] + bias;
      v = v > 0.f ? v : 0.f;
      act[quad*4 + r][nt*16 + m] = f2b(v);
    }
  }
  __syncthreads();

  bf16x8 hf[5];

  // ---- layer 1 ----
  #pragma unroll
  for(int ki = 0; ki < 5; ++ki)
    hf[ki] = *(const bf16x8*)&act[m][ki*32 + quad*8];
  __syncthreads();
  #pragma unroll
  for(int nt = 0; nt < 9; ++nt){
    f32x4 acc = {0.f,0.f,0.f,0.f};
    const unsigned short* wr = w1p + (size_t)(nt*16 + m)*KP + quad*8;
    #pragma unroll
    for(int ki = 0; ki < 5; ++ki){
      bf16x8 wf = *(const bf16x8*)(wr + ki*32);
      acc = __builtin_amdgcn_mfma_f32_16x16x32_bf16(hf[ki], wf, acc, 0, 0, 0);
    }
    float bias = b1p[nt*16 + m];
    #pragma unroll
    for(int r = 0; r < 4; ++r){
      float v = acc[r] + bias;
      v = v > 0.f ? v : 0.f;
      act[quad*4 + r][nt*16 + m] = f2b(v);
    }
  }
  __syncthreads();

  // ---- layer 2 ----
  #pragma unroll
  for(int ki = 0; ki < 5; ++ki)
    hf[ki] = *(const bf16x8*)&act[m][ki*32 + quad*8];
  __syncthreads();
  #pragma unroll
  for(int nt = 0; nt < 9; ++nt){
    f32x4 acc = {0.f,0.f,0.f,0.f};
    const unsigned short* wr = w2p + (size_t)(nt*16 + m)*KP + quad*8;
    #pragma unroll
    for(int ki = 0; ki < 5; ++ki){
      bf16x8 wf = *(const bf16x8*)(wr + ki*32);
      acc = __builtin_amdgcn_mfma_f32_16x16x32_bf16(hf[ki], wf, acc, 0, 0, 0);
    }
    float bias = b2p[nt*16 + m];
    #pragma unroll
    for(int r = 0; r < 4; ++r){
      float v = acc[r] + bias;
      v = v > 0.f ? v : 0.f;
      act[quad*4 + r][nt*16 + m] = f2b(v);
    }
  }
  __syncthreads();

  // ---- layer 3: out = h2 @ W3^T + b3  [N=128, K=160], fp32 output ----
  #pragma unroll
  for(int ki = 0; ki < 5; ++ki)
    hf[ki] = *(const bf16x8*)&act[m][ki*32 + quad*8];
  #pragma unroll
  for(int nt = 0; nt < 8; ++nt){
    f32x4 acc = {0.f,0.f,0.f,0.f};
    const unsigned short* wr = w3p + (size_t)(nt*16 + m)*KP + quad*8;
    #pragma unroll
    for(int ki = 0; ki < 5; ++ki){
      bf16x8 wf = *(const bf16x8*)(wr + ki*32);
      acc = __builtin_amdgcn_mfma_f32_16x16x32_bf16(hf[ki], wf, acc, 0, 0, 0);
    }
    float bias = b3p[nt*16 + m];
    #pragma unroll
    for(int r = 0; r < 4; ++r){
      int grow = rowBase + quad*4 + r;
      out[(size_t)grow*DD + nt*16 + m] = acc[r] + bias;
    }
  }
}

extern "C" void kernel_launch(void* const* d_in, const int* in_sizes, int n_in,
                              void* d_out, int out_size, void* d_ws, size_t ws_size,
                              hipStream_t stream){
  const float* signal = (const float*)d_in[0];
  const float* comps  = (const float*)d_in[1];
  const float* Wm = (const float*)d_in[2];
  const float* bm = (const float*)d_in[3];
  const float* Wu = (const float*)d_in[4];
  const float* bu = (const float*)d_in[5];
  const float* W0 = (const float*)d_in[6];
  const float* b0 = (const float*)d_in[7];
  const float* W1 = (const float*)d_in[8];
  const float* b1 = (const float*)d_in[9];
  const float* W2 = (const float*)d_in[10];
  const float* b2 = (const float*)d_in[11];
  const float* W3 = (const float*)d_in[12];
  const float* b3 = (const float*)d_in[13];

  char* ws = (char*)d_ws;
  float*          Wf    = (float*)(ws + 0);        // 128*128*4 = 65536
  float*          bfv   = (float*)(ws + 65536);    // 512
  unsigned short* w0s_p = (unsigned short*)(ws + 66048);   // 36864
  unsigned short* w0rp  = (unsigned short*)(ws + 102912);  // 36864
  unsigned short* w1p   = (unsigned short*)(ws + 139776);  // 46080
  unsigned short* w2p   = (unsigned short*)(ws + 185856);  // 46080
  unsigned short* w3p   = (unsigned short*)(ws + 231936);  // 40960
  float*          b0p   = (float*)(ws + 272896);   // 576
  float*          b1p   = (float*)(ws + 273472);
  float*          b2p   = (float*)(ws + 274048);
  float*          b3p   = (float*)(ws + 274624);
  unsigned short* sumb  = (unsigned short*)(ws + 275456);  // B*D*2 = 16.8 MB

  // K1: streaming component sum (independent of preps)
  hipLaunchKernelGGL(comp_sum, dim3(BB*DD/4/256), dim3(256), 0, stream, comps, sumb);

  hipLaunchKernelGGL(prepA, dim3(64), dim3(256), 0, stream, Wm, bm, Wu, bu, Wf, bfv);

  hipLaunchKernelGGL(prepB, dim3(407), dim3(256), 0, stream,
                     W0, b0, W1, b1, W2, b2, W3, b3, Wf, bfv,
                     w0s_p, w0rp, w1p, w2p, w3p, b0p, b1p, b2p, b3p);

  hipLaunchKernelGGL(fused_mlp, dim3(BB/16), dim3(64), 0, stream,
                     signal, sumb, w0s_p, w0rp, w1p, w2p, w3p,
                     b0p, b1p, b2p, b3p, (float*)d_out);
}

// Round 4
// 498.468 us; speedup vs baseline: 1.0049x; 1.0049x over previous
//
#include <hip/hip_runtime.h>
#include <stdint.h>

// Problem constants
#define DD  128     // latent dim
#define HH  132     // FCBlock hidden width
#define BB  65536   // batch
#define KKC 8       // num components
#define HP  144     // padded hidden (N-dim, 9 tiles of 16)
#define KP  160     // padded K-dim for hidden layers (5 steps of 32)

typedef short bf16x8 __attribute__((ext_vector_type(8)));
typedef short bf16x4 __attribute__((ext_vector_type(4)));
typedef float f32x4  __attribute__((ext_vector_type(4)));

__device__ __forceinline__ unsigned short f2b(float f){
  union{float f; unsigned u;} c; c.f = f;
  unsigned r = c.u + 0x7fffu + ((c.u >> 16) & 1u);   // RNE
  return (unsigned short)(r >> 16);
}

// ---------------- prep A: Wf = Wu @ Wm (fp32), bfv = K*(Wu@bm) + bu ----------------
__global__ void prepA(const float* __restrict__ Wm, const float* __restrict__ bm,
                      const float* __restrict__ Wu, const float* __restrict__ bu,
                      float* __restrict__ Wf, float* __restrict__ bfv){
  int idx = blockIdx.x * 256 + threadIdx.x;      // 64 blocks -> 16384 = 128*128
  int i = idx >> 7, j = idx & 127;
  float acc = 0.f;
  for(int d = 0; d < DD; ++d)
    acc += Wu[i*DD + d] * Wm[d*DD + j];
  Wf[idx] = acc;
  if(j == 0){
    float a = 0.f;
    for(int d = 0; d < DD; ++d) a += Wu[i*DD + d] * bm[d];
    bfv[i] = (float)KKC * a + bu[i];
  }
}

// ---------------- prep B: fused + padded bf16 weights into workspace ----------------
__global__ void prepB(const float* __restrict__ W0, const float* __restrict__ b0,
                      const float* __restrict__ W1, const float* __restrict__ b1,
                      const float* __restrict__ W2, const float* __restrict__ b2,
                      const float* __restrict__ W3, const float* __restrict__ b3,
                      const float* __restrict__ Wf, const float* __restrict__ bfv,
                      unsigned short* __restrict__ w0s_p, unsigned short* __restrict__ w0rp,
                      unsigned short* __restrict__ w1p,  unsigned short* __restrict__ w2p,
                      unsigned short* __restrict__ w3p,
                      float* __restrict__ b0p, float* __restrict__ b1p,
                      float* __restrict__ b2p, float* __restrict__ b3p){
  int idx = blockIdx.x * 256 + threadIdx.x;
  if(idx < HP*DD){                                  // w0s_p: signal half of W0, padded
    int n = idx >> 7, k = idx & 127;
    w0s_p[idx] = (n < HH) ? f2b(W0[n*(2*DD) + k]) : (unsigned short)0;
    return;
  }
  idx -= HP*DD;
  if(idx < HP*DD){                                  // w0rp = W0r @ Wf, padded
    int n = idx >> 7, k = idx & 127;
    float acc = 0.f;
    if(n < HH)
      for(int i = 0; i < DD; ++i)
        acc += W0[n*(2*DD) + DD + i] * Wf[i*DD + k];
    w0rp[idx] = (n < HH) ? f2b(acc) : (unsigned short)0;
    return;
  }
  idx -= HP*DD;
  if(idx < HP*KP){                                  // w1p padded
    int n = idx / KP, k = idx % KP;
    w1p[idx] = (n < HH && k < HH) ? f2b(W1[n*HH + k]) : (unsigned short)0;
    return;
  }
  idx -= HP*KP;
  if(idx < HP*KP){                                  // w2p padded
    int n = idx / KP, k = idx % KP;
    w2p[idx] = (n < HH && k < HH) ? f2b(W2[n*HH + k]) : (unsigned short)0;
    return;
  }
  idx -= HP*KP;
  if(idx < DD*KP){                                  // w3p padded (N=128 full, K pad)
    int n = idx / KP, k = idx % KP;
    w3p[idx] = (k < HH) ? f2b(W3[n*HH + k]) : (unsigned short)0;
    return;
  }
  idx -= DD*KP;
  if(idx < HP){                                     // b0p = b0 + W0r @ bfv, padded
    float acc = 0.f;
    if(idx < HH){
      acc = b0[idx];
      for(int i = 0; i < DD; ++i) acc += W0[idx*(2*DD) + DD + i] * bfv[i];
    }
    b0p[idx] = acc;
    return;
  }
  idx -= HP;
  if(idx < HP){ b1p[idx] = (idx < HH) ? b1[idx] : 0.f; return; }
  idx -= HP;
  if(idx < HP){ b2p[idx] = (idx < HH) ? b2[idx] : 0.f; return; }
  idx -= HP;
  if(idx < DD){ b3p[idx] = b3[idx]; return; }
}

// ---------------- K1: pure streaming component sum -> bf16 [B,D] ----------------
// 8192 blocks x 256 threads; 8 independent 16B loads/thread, one 8B store.
// Low VGPR -> 8 waves/SIMD for max memory-level parallelism.
__global__ __launch_bounds__(256, 8) void comp_sum(
    const float* __restrict__ comps, unsigned short* __restrict__ sumb){
  const size_t idx4 = ((size_t)blockIdx.x * 256 + threadIdx.x) * 4;
  f32x4 a = {0.f,0.f,0.f,0.f};
  #pragma unroll
  for(int k = 0; k < KKC; ++k){
    f32x4 v = *(const f32x4*)(comps + (size_t)k * BB * DD + idx4);
    a += v;
  }
  bf16x4 p;
  #pragma unroll
  for(int j = 0; j < 4; ++j) p[j] = (short)f2b(a[j]);
  *(bf16x4*)(sumb + idx4) = p;
}

// ---------------- K2: fused 4-layer MLP ----------------
// 256 threads = 4 waves; each wave owns 16 rows -> 64 rows/block. Grid = 1024.
// (R2-proven structure: weight working set fetched once per 64 rows, waves
//  within a block share weights through L1.)
// MFMA 16x16x32 bf16 layouts:
//   A frag : lane holds A[m=lane&15][k = (lane>>4)*8 + j], j=0..7
//   B frag : lane holds B[k][n=lane&15] -> W[n][k..k+7] row-major 16B
//   C/D    : lane holds D[row = (lane>>4)*4 + r][col = lane&15]
__global__ __launch_bounds__(256) void fused_mlp(
    const float* __restrict__ signal,
    const unsigned short* __restrict__ sumb,
    const unsigned short* __restrict__ w0s_p,
    const unsigned short* __restrict__ w0rp,
    const unsigned short* __restrict__ w1p,
    const unsigned short* __restrict__ w2p,
    const unsigned short* __restrict__ w3p,
    const float* __restrict__ b0p, const float* __restrict__ b1p,
    const float* __restrict__ b2p, const float* __restrict__ b3p,
    float* __restrict__ out)
{
  const int tid  = threadIdx.x;
  const int lane = tid & 63;
  const int wave = tid >> 6;
  const int m    = lane & 15;
  const int quad = lane >> 4;
  const int rowBase = blockIdx.x * 64 + wave * 16;
  const int arow = rowBase + m;

  // per-wave private 16 x KP tile; stride 168 keeps ds_read_b128 conflicts minor
  __shared__ unsigned short act[4][16][168];

  // zero the K-pad columns [144,160)
  for(int t = tid; t < 4*16*16; t += 256){
    int wv = t >> 8, r = (t >> 4) & 15, c = t & 15;
    act[wv][r][144 + c] = 0;
  }
  __syncthreads();

  // ---- A-fragments: sum (bf16 direct) and signal (fp32 -> bf16) ----
  bf16x8 sumf[4];
  #pragma unroll
  for(int ki = 0; ki < 4; ++ki)
    sumf[ki] = *(const bf16x8*)(sumb + (size_t)arow*DD + ki*32 + quad*8);

  bf16x8 sigf[4];
  {
    const float* srow = signal + (size_t)arow * DD;
    #pragma unroll
    for(int ki = 0; ki < 4; ++ki){
      f32x4 lo = *(const f32x4*)(srow + ki*32 + quad*8);
      f32x4 hi = *(const f32x4*)(srow + ki*32 + quad*8 + 4);
      bf16x8 p;
      #pragma unroll
      for(int j = 0; j < 4; ++j){ p[j] = (short)f2b(lo[j]); p[4+j] = (short)f2b(hi[j]); }
      sigf[ki] = p;
    }
  }

  // ---- layer 0: h0 = relu(sig @ W0s^T + sum @ W0rp^T + b0p)  [N=144, K=128+128]
  #pragma unroll
  for(int nt = 0; nt < 9; ++nt){
    f32x4 acc = {0.f,0.f,0.f,0.f};
    const unsigned short* wr1 = w0s_p + (size_t)(nt*16 + m)*DD + quad*8;
    const unsigned short* wr2 = w0rp  + (size_t)(nt*16 + m)*DD + quad*8;
    #pragma unroll
    for(int ki = 0; ki < 4; ++ki){
      bf16x8 wf = *(const bf16x8*)(wr1 + ki*32);
      acc = __builtin_amdgcn_mfma_f32_16x16x32_bf16(sigf[ki], wf, acc, 0, 0, 0);
    }
    #pragma unroll
    for(int ki = 0; ki < 4; ++ki){
      bf16x8 wf = *(const bf16x8*)(wr2 + ki*32);
      acc = __builtin_amdgcn_mfma_f32_16x16x32_bf16(sumf[ki], wf, acc, 0, 0, 0);
    }
    float bias = b0p[nt*16 + m];
    #pragma unroll
    for(int r = 0; r < 4; ++r){
      float v = acc[r] + bias;
      v = v > 0.f ? v : 0.f;
      act[wave][quad*4 + r][nt*16 + m] = f2b(v);
    }
  }
  __syncthreads();

  bf16x8 hf[5];

  // ---- layer 1 ----
  #pragma unroll
  for(int ki = 0; ki < 5; ++ki)
    hf[ki] = *(const bf16x8*)&act[wave][m][ki*32 + quad*8];
  __syncthreads();
  #pragma unroll
  for(int nt = 0; nt < 9; ++nt){
    f32x4 acc = {0.f,0.f,0.f,0.f};
    const unsigned short* wr = w1p + (size_t)(nt*16 + m)*KP + quad*8;
    #pragma unroll
    for(int ki = 0; ki < 5; ++ki){
      bf16x8 wf = *(const bf16x8*)(wr + ki*32);
      acc = __builtin_amdgcn_mfma_f32_16x16x32_bf16(hf[ki], wf, acc, 0, 0, 0);
    }
    float bias = b1p[nt*16 + m];
    #pragma unroll
    for(int r = 0; r < 4; ++r){
      float v = acc[r] + bias;
      v = v > 0.f ? v : 0.f;
      act[wave][quad*4 + r][nt*16 + m] = f2b(v);
    }
  }
  __syncthreads();

  // ---- layer 2 ----
  #pragma unroll
  for(int ki = 0; ki < 5; ++ki)
    hf[ki] = *(const bf16x8*)&act[wave][m][ki*32 + quad*8];
  __syncthreads();
  #pragma unroll
  for(int nt = 0; nt < 9; ++nt){
    f32x4 acc = {0.f,0.f,0.f,0.f};
    const unsigned short* wr = w2p + (size_t)(nt*16 + m)*KP + quad*8;
    #pragma unroll
    for(int ki = 0; ki < 5; ++ki){
      bf16x8 wf = *(const bf16x8*)(wr + ki*32);
      acc = __builtin_amdgcn_mfma_f32_16x16x32_bf16(hf[ki], wf, acc, 0, 0, 0);
    }
    float bias = b2p[nt*16 + m];
    #pragma unroll
    for(int r = 0; r < 4; ++r){
      float v = acc[r] + bias;
      v = v > 0.f ? v : 0.f;
      act[wave][quad*4 + r][nt*16 + m] = f2b(v);
    }
  }
  __syncthreads();

  // ---- layer 3: out = h2 @ W3^T + b3  [N=128, K=160], fp32 output ----
  #pragma unroll
  for(int ki = 0; ki < 5; ++ki)
    hf[ki] = *(const bf16x8*)&act[wave][m][ki*32 + quad*8];
  #pragma unroll
  for(int nt = 0; nt < 8; ++nt){
    f32x4 acc = {0.f,0.f,0.f,0.f};
    const unsigned short* wr = w3p + (size_t)(nt*16 + m)*KP + quad*8;
    #pragma unroll
    for(int ki = 0; ki < 5; ++ki){
      bf16x8 wf = *(const bf16x8*)(wr + ki*32);
      acc = __builtin_amdgcn_mfma_f32_16x16x32_bf16(hf[ki], wf, acc, 0, 0, 0);
    }
    float bias = b3p[nt*16 + m];
    #pragma unroll
    for(int r = 0; r < 4; ++r){
      int grow = rowBase + quad*4 + r;
      out[(size_t)grow*DD + nt*16 + m] = acc[r] + bias;
    }
  }
}

extern "C" void kernel_launch(void* const* d_in, const int* in_sizes, int n_in,
                              void* d_out, int out_size, void* d_ws, size_t ws_size,
                              hipStream_t stream){
  const float* signal = (const float*)d_in[0];
  const float* comps  = (const float*)d_in[1];
  const float* Wm = (const float*)d_in[2];
  const float* bm = (const float*)d_in[3];
  const float* Wu = (const float*)d_in[4];
  const float* bu = (const float*)d_in[5];
  const float* W0 = (const float*)d_in[6];
  const float* b0 = (const float*)d_in[7];
  const float* W1 = (const float*)d_in[8];
  const float* b1 = (const float*)d_in[9];
  const float* W2 = (const float*)d_in[10];
  const float* b2 = (const float*)d_in[11];
  const float* W3 = (const float*)d_in[12];
  const float* b3 = (const float*)d_in[13];

  char* ws = (char*)d_ws;
  float*          Wf    = (float*)(ws + 0);        // 128*128*4 = 65536
  float*          bfv   = (float*)(ws + 65536);    // 512
  unsigned short* w0s_p = (unsigned short*)(ws + 66048);   // 36864
  unsigned short* w0rp  = (unsigned short*)(ws + 102912);  // 36864
  unsigned short* w1p   = (unsigned short*)(ws + 139776);  // 46080
  unsigned short* w2p   = (unsigned short*)(ws + 185856);  // 46080
  unsigned short* w3p   = (unsigned short*)(ws + 231936);  // 40960
  float*          b0p   = (float*)(ws + 272896);   // 576
  float*          b1p   = (float*)(ws + 273472);
  float*          b2p   = (float*)(ws + 274048);
  float*          b3p   = (float*)(ws + 274624);
  unsigned short* sumb  = (unsigned short*)(ws + 275456);  // B*D*2 = 16.8 MB

  hipLaunchKernelGGL(prepA, dim3(64), dim3(256), 0, stream, Wm, bm, Wu, bu, Wf, bfv);

  hipLaunchKernelGGL(prepB, dim3(407), dim3(256), 0, stream,
                     W0, b0, W1, b1, W2, b2, W3, b3, Wf, bfv,
                     w0s_p, w0rp, w1p, w2p, w3p, b0p, b1p, b2p, b3p);

  hipLaunchKernelGGL(comp_sum, dim3(BB*DD/4/256), dim3(256), 0, stream, comps, sumb);

  hipLaunchKernelGGL(fused_mlp, dim3(BB/64), dim3(256), 0, stream,
                     signal, sumb, w0s_p, w0rp, w1p, w2p, w3p,
                     b0p, b1p, b2p, b3p, (float*)d_out);
}

// Round 5
// 491.616 us; speedup vs baseline: 1.0189x; 1.0139x over previous
//
#include <hip/hip_runtime.h>
#include <stdint.h>

// Problem constants
#define DD  128     // latent dim
#define HH  132     // FCBlock hidden width
#define BB  65536   // batch
#define KKC 8       // num components
#define HP  144     // padded hidden (N-dim, 9 tiles of 16)
#define KP  160     // padded K-dim for hidden layers (5 steps of 32)

typedef short bf16x8 __attribute__((ext_vector_type(8)));
typedef short bf16x4 __attribute__((ext_vector_type(4)));
typedef float f32x4  __attribute__((ext_vector_type(4)));

__device__ __forceinline__ unsigned short f2b(float f){
  union{float f; unsigned u;} c; c.f = f;
  unsigned r = c.u + 0x7fffu + ((c.u >> 16) & 1u);   // RNE
  return (unsigned short)(r >> 16);
}

// ---------------- prep A: Wf = Wu @ Wm (fp32), bfv = K*(Wu@bm) + bu ----------------
__global__ void prepA(const float* __restrict__ Wm, const float* __restrict__ bm,
                      const float* __restrict__ Wu, const float* __restrict__ bu,
                      float* __restrict__ Wf, float* __restrict__ bfv){
  int idx = blockIdx.x * 256 + threadIdx.x;      // 64 blocks -> 16384 = 128*128
  int i = idx >> 7, j = idx & 127;
  float acc = 0.f;
  for(int d = 0; d < DD; ++d)
    acc += Wu[i*DD + d] * Wm[d*DD + j];
  Wf[idx] = acc;
  if(j == 0){
    float a = 0.f;
    for(int d = 0; d < DD; ++d) a += Wu[i*DD + d] * bm[d];
    bfv[i] = (float)KKC * a + bu[i];
  }
}

// ---------------- prep B: fused + padded bf16 weights into workspace ----------------
__global__ void prepB(const float* __restrict__ W0, const float* __restrict__ b0,
                      const float* __restrict__ W1, const float* __restrict__ b1,
                      const float* __restrict__ W2, const float* __restrict__ b2,
                      const float* __restrict__ W3, const float* __restrict__ b3,
                      const float* __restrict__ Wf, const float* __restrict__ bfv,
                      unsigned short* __restrict__ w0s_p, unsigned short* __restrict__ w0rp,
                      unsigned short* __restrict__ w1p,  unsigned short* __restrict__ w2p,
                      unsigned short* __restrict__ w3p,
                      float* __restrict__ b0p, float* __restrict__ b1p,
                      float* __restrict__ b2p, float* __restrict__ b3p){
  int idx = blockIdx.x * 256 + threadIdx.x;
  if(idx < HP*DD){                                  // w0s_p: signal half of W0, padded
    int n = idx >> 7, k = idx & 127;
    w0s_p[idx] = (n < HH) ? f2b(W0[n*(2*DD) + k]) : (unsigned short)0;
    return;
  }
  idx -= HP*DD;
  if(idx < HP*DD){                                  // w0rp = W0r @ Wf, padded
    int n = idx >> 7, k = idx & 127;
    float acc = 0.f;
    if(n < HH)
      for(int i = 0; i < DD; ++i)
        acc += W0[n*(2*DD) + DD + i] * Wf[i*DD + k];
    w0rp[idx] = (n < HH) ? f2b(acc) : (unsigned short)0;
    return;
  }
  idx -= HP*DD;
  if(idx < HP*KP){                                  // w1p padded
    int n = idx / KP, k = idx % KP;
    w1p[idx] = (n < HH && k < HH) ? f2b(W1[n*HH + k]) : (unsigned short)0;
    return;
  }
  idx -= HP*KP;
  if(idx < HP*KP){                                  // w2p padded
    int n = idx / KP, k = idx % KP;
    w2p[idx] = (n < HH && k < HH) ? f2b(W2[n*HH + k]) : (unsigned short)0;
    return;
  }
  idx -= HP*KP;
  if(idx < DD*KP){                                  // w3p padded (N=128 full, K pad)
    int n = idx / KP, k = idx % KP;
    w3p[idx] = (k < HH) ? f2b(W3[n*HH + k]) : (unsigned short)0;
    return;
  }
  idx -= DD*KP;
  if(idx < HP){                                     // b0p = b0 + W0r @ bfv, padded
    float acc = 0.f;
    if(idx < HH){
      acc = b0[idx];
      for(int i = 0; i < DD; ++i) acc += W0[idx*(2*DD) + DD + i] * bfv[i];
    }
    b0p[idx] = acc;
    return;
  }
  idx -= HP;
  if(idx < HP){ b1p[idx] = (idx < HH) ? b1[idx] : 0.f; return; }
  idx -= HP;
  if(idx < HP){ b2p[idx] = (idx < HH) ? b2[idx] : 0.f; return; }
  idx -= HP;
  if(idx < DD){ b3p[idx] = b3[idx]; return; }
}

// ---------------- K1: streaming component sum, row-thrash-free ----------------
// Each block owns 8192 contiguous elements (32 KB per component slice).
// k is the OUTER serial loop: within one k the block streams 32 KB linearly
// (8 x 4 KB coalesced rounds) -> HBM rows stay open; the 2^25-byte bank-aliased
// stride is only crossed once per 32 KB of linear traffic (vs once per 16 B in
// the previous version, which thrashed every bank's row buffer at ~1.9 TB/s).
__global__ __launch_bounds__(256) void comp_sum(
    const float* __restrict__ comps, unsigned short* __restrict__ sumb){
  const size_t base = (size_t)blockIdx.x * 8192;   // element base of this block
  const int t = threadIdx.x;
  f32x4 acc[8];
  #pragma unroll
  for(int i = 0; i < 8; ++i) acc[i] = (f32x4){0.f,0.f,0.f,0.f};

  #pragma unroll
  for(int k = 0; k < KKC; ++k){
    const float* p = comps + (size_t)k * BB * DD + base + t*4;
    #pragma unroll
    for(int i = 0; i < 8; ++i){
      f32x4 v = *(const f32x4*)(p + i*1024);       // 4 KB apart; wave covers 1 KB contiguous
      acc[i] += v;
    }
  }
  unsigned short* q = sumb + base + t*4;
  #pragma unroll
  for(int i = 0; i < 8; ++i){
    bf16x4 pk;
    #pragma unroll
    for(int j = 0; j < 4; ++j) pk[j] = (short)f2b(acc[i][j]);
    *(bf16x4*)(q + i*1024) = pk;
  }
}

// ---------------- K2: fused 4-layer MLP ----------------
// 256 threads = 4 waves; each wave owns 16 rows -> 64 rows/block. Grid = 1024.
// MFMA 16x16x32 bf16 layouts:
//   A frag : lane holds A[m=lane&15][k = (lane>>4)*8 + j], j=0..7
//   B frag : lane holds B[k][n=lane&15] -> W[n][k..k+7] row-major 16B
//   C/D    : lane holds D[row = (lane>>4)*4 + r][col = lane&15]
__global__ __launch_bounds__(256) void fused_mlp(
    const float* __restrict__ signal,
    const unsigned short* __restrict__ sumb,
    const unsigned short* __restrict__ w0s_p,
    const unsigned short* __restrict__ w0rp,
    const unsigned short* __restrict__ w1p,
    const unsigned short* __restrict__ w2p,
    const unsigned short* __restrict__ w3p,
    const float* __restrict__ b0p, const float* __restrict__ b1p,
    const float* __restrict__ b2p, const float* __restrict__ b3p,
    float* __restrict__ out)
{
  const int tid  = threadIdx.x;
  const int lane = tid & 63;
  const int wave = tid >> 6;
  const int m    = lane & 15;
  const int quad = lane >> 4;
  const int rowBase = blockIdx.x * 64 + wave * 16;
  const int arow = rowBase + m;

  // per-wave private 16 x KP tile; stride 168 keeps ds_read_b128 conflicts minor
  __shared__ unsigned short act[4][16][168];

  // zero the K-pad columns [144,160)
  for(int t = tid; t < 4*16*16; t += 256){
    int wv = t >> 8, r = (t >> 4) & 15, c = t & 15;
    act[wv][r][144 + c] = 0;
  }
  __syncthreads();

  // ---- A-fragments: sum (bf16 direct) and signal (fp32 -> bf16) ----
  bf16x8 sumf[4];
  #pragma unroll
  for(int ki = 0; ki < 4; ++ki)
    sumf[ki] = *(const bf16x8*)(sumb + (size_t)arow*DD + ki*32 + quad*8);

  bf16x8 sigf[4];
  {
    const float* srow = signal + (size_t)arow * DD;
    #pragma unroll
    for(int ki = 0; ki < 4; ++ki){
      f32x4 lo = *(const f32x4*)(srow + ki*32 + quad*8);
      f32x4 hi = *(const f32x4*)(srow + ki*32 + quad*8 + 4);
      bf16x8 p;
      #pragma unroll
      for(int j = 0; j < 4; ++j){ p[j] = (short)f2b(lo[j]); p[4+j] = (short)f2b(hi[j]); }
      sigf[ki] = p;
    }
  }

  // ---- layer 0: h0 = relu(sig @ W0s^T + sum @ W0rp^T + b0p)  [N=144, K=128+128]
  #pragma unroll
  for(int nt = 0; nt < 9; ++nt){
    f32x4 acc = {0.f,0.f,0.f,0.f};
    const unsigned short* wr1 = w0s_p + (size_t)(nt*16 + m)*DD + quad*8;
    const unsigned short* wr2 = w0rp  + (size_t)(nt*16 + m)*DD + quad*8;
    #pragma unroll
    for(int ki = 0; ki < 4; ++ki){
      bf16x8 wf = *(const bf16x8*)(wr1 + ki*32);
      acc = __builtin_amdgcn_mfma_f32_16x16x32_bf16(sigf[ki], wf, acc, 0, 0, 0);
    }
    #pragma unroll
    for(int ki = 0; ki < 4; ++ki){
      bf16x8 wf = *(const bf16x8*)(wr2 + ki*32);
      acc = __builtin_amdgcn_mfma_f32_16x16x32_bf16(sumf[ki], wf, acc, 0, 0, 0);
    }
    float bias = b0p[nt*16 + m];
    #pragma unroll
    for(int r = 0; r < 4; ++r){
      float v = acc[r] + bias;
      v = v > 0.f ? v : 0.f;
      act[wave][quad*4 + r][nt*16 + m] = f2b(v);
    }
  }
  __syncthreads();

  bf16x8 hf[5];

  // ---- layer 1 ----
  #pragma unroll
  for(int ki = 0; ki < 5; ++ki)
    hf[ki] = *(const bf16x8*)&act[wave][m][ki*32 + quad*8];
  __syncthreads();
  #pragma unroll
  for(int nt = 0; nt < 9; ++nt){
    f32x4 acc = {0.f,0.f,0.f,0.f};
    const unsigned short* wr = w1p + (size_t)(nt*16 + m)*KP + quad*8;
    #pragma unroll
    for(int ki = 0; ki < 5; ++ki){
      bf16x8 wf = *(const bf16x8*)(wr + ki*32);
      acc = __builtin_amdgcn_mfma_f32_16x16x32_bf16(hf[ki], wf, acc, 0, 0, 0);
    }
    float bias = b1p[nt*16 + m];
    #pragma unroll
    for(int r = 0; r < 4; ++r){
      float v = acc[r] + bias;
      v = v > 0.f ? v : 0.f;
      act[wave][quad*4 + r][nt*16 + m] = f2b(v);
    }
  }
  __syncthreads();

  // ---- layer 2 ----
  #pragma unroll
  for(int ki = 0; ki < 5; ++ki)
    hf[ki] = *(const bf16x8*)&act[wave][m][ki*32 + quad*8];
  __syncthreads();
  #pragma unroll
  for(int nt = 0; nt < 9; ++nt){
    f32x4 acc = {0.f,0.f,0.f,0.f};
    const unsigned short* wr = w2p + (size_t)(nt*16 + m)*KP + quad*8;
    #pragma unroll
    for(int ki = 0; ki < 5; ++ki){
      bf16x8 wf = *(const bf16x8*)(wr + ki*32);
      acc = __builtin_amdgcn_mfma_f32_16x16x32_bf16(hf[ki], wf, acc, 0, 0, 0);
    }
    float bias = b2p[nt*16 + m];
    #pragma unroll
    for(int r = 0; r < 4; ++r){
      float v = acc[r] + bias;
      v = v > 0.f ? v : 0.f;
      act[wave][quad*4 + r][nt*16 + m] = f2b(v);
    }
  }
  __syncthreads();

  // ---- layer 3: out = h2 @ W3^T + b3  [N=128, K=160], fp32 output ----
  #pragma unroll
  for(int ki = 0; ki < 5; ++ki)
    hf[ki] = *(const bf16x8*)&act[wave][m][ki*32 + quad*8];
  #pragma unroll
  for(int nt = 0; nt < 8; ++nt){
    f32x4 acc = {0.f,0.f,0.f,0.f};
    const unsigned short* wr = w3p + (size_t)(nt*16 + m)*KP + quad*8;
    #pragma unroll
    for(int ki = 0; ki < 5; ++ki){
      bf16x8 wf = *(const bf16x8*)(wr + ki*32);
      acc = __builtin_amdgcn_mfma_f32_16x16x32_bf16(hf[ki], wf, acc, 0, 0, 0);
    }
    float bias = b3p[nt*16 + m];
    #pragma unroll
    for(int r = 0; r < 4; ++r){
      int grow = rowBase + quad*4 + r;
      out[(size_t)grow*DD + nt*16 + m] = acc[r] + bias;
    }
  }
}

extern "C" void kernel_launch(void* const* d_in, const int* in_sizes, int n_in,
                              void* d_out, int out_size, void* d_ws, size_t ws_size,
                              hipStream_t stream){
  const float* signal = (const float*)d_in[0];
  const float* comps  = (const float*)d_in[1];
  const float* Wm = (const float*)d_in[2];
  const float* bm = (const float*)d_in[3];
  const float* Wu = (const float*)d_in[4];
  const float* bu = (const float*)d_in[5];
  const float* W0 = (const float*)d_in[6];
  const float* b0 = (const float*)d_in[7];
  const float* W1 = (const float*)d_in[8];
  const float* b1 = (const float*)d_in[9];
  const float* W2 = (const float*)d_in[10];
  const float* b2 = (const float*)d_in[11];
  const float* W3 = (const float*)d_in[12];
  const float* b3 = (const float*)d_in[13];

  char* ws = (char*)d_ws;
  float*          Wf    = (float*)(ws + 0);        // 128*128*4 = 65536
  float*          bfv   = (float*)(ws + 65536);    // 512
  unsigned short* w0s_p = (unsigned short*)(ws + 66048);   // 36864
  unsigned short* w0rp  = (unsigned short*)(ws + 102912);  // 36864
  unsigned short* w1p   = (unsigned short*)(ws + 139776);  // 46080
  unsigned short* w2p   = (unsigned short*)(ws + 185856);  // 46080
  unsigned short* w3p   = (unsigned short*)(ws + 231936);  // 40960
  float*          b0p   = (float*)(ws + 272896);   // 576
  float*          b1p   = (float*)(ws + 273472);
  float*          b2p   = (float*)(ws + 274048);
  float*          b3p   = (float*)(ws + 274624);
  unsigned short* sumb  = (unsigned short*)(ws + 275456);  // B*D*2 = 16.8 MB

  hipLaunchKernelGGL(prepA, dim3(64), dim3(256), 0, stream, Wm, bm, Wu, bu, Wf, bfv);

  hipLaunchKernelGGL(prepB, dim3(407), dim3(256), 0, stream,
                     W0, b0, W1, b1, W2, b2, W3, b3, Wf, bfv,
                     w0s_p, w0rp, w1p, w2p, w3p, b0p, b1p, b2p, b3p);

  // 8,388,608 elements / 8192 per block = 1024 blocks
  hipLaunchKernelGGL(comp_sum, dim3(BB*DD/8192), dim3(256), 0, stream, comps, sumb);

  hipLaunchKernelGGL(fused_mlp, dim3(BB/64), dim3(256), 0, stream,
                     signal, sumb, w0s_p, w0rp, w1p, w2p, w3p,
                     b0p, b1p, b2p, b3p, (float*)d_out);
}

// Round 6
// 451.288 us; speedup vs baseline: 1.1099x; 1.0894x over previous
//
#include <hip/hip_runtime.h>
#include <stdint.h>

// Problem constants
#define DD  128     // latent dim
#define HH  132     // FCBlock hidden width
#define BB  65536   // batch
#define KKC 8       // num components
#define HP  144     // padded hidden (N-dim, 9 tiles of 16)
#define KP  160     // padded K-dim for hidden layers (5 steps of 32)
#define SW  136     // LDS-friendly row stride (elems) for K=128 weight arrays
#define SH  168     // LDS-friendly row stride (elems) for K=160 weight arrays
// region sizes (bytes), padded to 512*16 multiples for uniform staging
#define W0S_BYTES 40960   // 20480 elems >= 144*136
#define WAB_BYTES 81920   // w0s || w0r
#define WH_BYTES  49152   // 24576 elems >= 144*168 (and >= 128*168)
#define ACT_BYTES 43008   // 8 waves * 16 * 168 * 2

typedef short bf16x8 __attribute__((ext_vector_type(8)));
typedef short bf16x4 __attribute__((ext_vector_type(4)));
typedef float f32x4  __attribute__((ext_vector_type(4)));

__device__ __forceinline__ unsigned short f2b(float f){
  union{float f; unsigned u;} c; c.f = f;
  unsigned r = c.u + 0x7fffu + ((c.u >> 16) & 1u);   // RNE
  return (unsigned short)(r >> 16);
}

// ---------------- prep A: Wf = Wu @ Wm (fp32), bfv = K*(Wu@bm) + bu ----------------
__global__ void prepA(const float* __restrict__ Wm, const float* __restrict__ bm,
                      const float* __restrict__ Wu, const float* __restrict__ bu,
                      float* __restrict__ Wf, float* __restrict__ bfv){
  int idx = blockIdx.x * 256 + threadIdx.x;      // 64 blocks -> 16384 = 128*128
  int i = idx >> 7, j = idx & 127;
  float acc = 0.f;
  for(int d = 0; d < DD; ++d)
    acc += Wu[i*DD + d] * Wm[d*DD + j];
  Wf[idx] = acc;
  if(j == 0){
    float a = 0.f;
    for(int d = 0; d < DD; ++d) a += Wu[i*DD + d] * bm[d];
    bfv[i] = (float)KKC * a + bu[i];
  }
}

// ---------------- prep B: fused + padded + re-strided bf16 weights ----------------
// wAB = [w0s (20480 el, rows 144 x stride 136) | w0r (same)]
// w1p/w2p: 24576 el, rows 144 x stride 168 (cols >=132 zero)
// w3p:     24576 el, rows 128 x stride 168
// All tails zeroed (staged into LDS; padded rows ARE read by MFMA -> must be 0).
__global__ void prepB(const float* __restrict__ W0, const float* __restrict__ b0,
                      const float* __restrict__ W1, const float* __restrict__ b1,
                      const float* __restrict__ W2, const float* __restrict__ b2,
                      const float* __restrict__ W3, const float* __restrict__ b3,
                      const float* __restrict__ Wf, const float* __restrict__ bfv,
                      unsigned short* __restrict__ wAB,
                      unsigned short* __restrict__ w1p, unsigned short* __restrict__ w2p,
                      unsigned short* __restrict__ w3p,
                      float* __restrict__ b0p, float* __restrict__ b1p,
                      float* __restrict__ b2p, float* __restrict__ b3p){
  int idx = blockIdx.x * 256 + threadIdx.x;
  if(idx < 20480){                                  // w0s: signal half of W0
    int n = idx / SW, c = idx % SW;
    wAB[idx] = (n < HH && c < DD) ? f2b(W0[n*(2*DD) + c]) : (unsigned short)0;
    return;
  }
  idx -= 20480;
  if(idx < 20480){                                  // w0r = W0r @ Wf
    int n = idx / SW, c = idx % SW;
    float acc = 0.f;
    bool live = (n < HH && c < DD);
    if(live)
      for(int i = 0; i < DD; ++i)
        acc += W0[n*(2*DD) + DD + i] * Wf[i*DD + c];
    wAB[20480 + idx] = live ? f2b(acc) : (unsigned short)0;
    return;
  }
  idx -= 20480;
  if(idx < 24576){                                  // w1p
    int n = idx / SH, c = idx % SH;
    w1p[idx] = (n < HH && c < HH) ? f2b(W1[n*HH + c]) : (unsigned short)0;
    return;
  }
  idx -= 24576;
  if(idx < 24576){                                  // w2p
    int n = idx / SH, c = idx % SH;
    w2p[idx] = (n < HH && c < HH) ? f2b(W2[n*HH + c]) : (unsigned short)0;
    return;
  }
  idx -= 24576;
  if(idx < 24576){                                  // w3p
    int n = idx / SH, c = idx % SH;
    w3p[idx] = (n < DD && c < HH) ? f2b(W3[n*HH + c]) : (unsigned short)0;
    return;
  }
  idx -= 24576;
  if(idx < HP){                                     // b0p = b0 + W0r @ bfv
    float acc = 0.f;
    if(idx < HH){
      acc = b0[idx];
      for(int i = 0; i < DD; ++i) acc += W0[idx*(2*DD) + DD + i] * bfv[i];
    }
    b0p[idx] = acc;
    return;
  }
  idx -= HP;
  if(idx < HP){ b1p[idx] = (idx < HH) ? b1[idx] : 0.f; return; }
  idx -= HP;
  if(idx < HP){ b2p[idx] = (idx < HH) ? b2[idx] : 0.f; return; }
  idx -= HP;
  if(idx < DD){ b3p[idx] = b3[idx]; return; }
}

// ---------------- K1: streaming component sum (at per-CU issue ceiling) ----------
__global__ __launch_bounds__(256) void comp_sum(
    const float* __restrict__ comps, unsigned short* __restrict__ sumb){
  const size_t base = (size_t)blockIdx.x * 8192;
  const int t = threadIdx.x;
  f32x4 acc[8];
  #pragma unroll
  for(int i = 0; i < 8; ++i) acc[i] = (f32x4){0.f,0.f,0.f,0.f};
  #pragma unroll
  for(int k = 0; k < KKC; ++k){
    const float* p = comps + (size_t)k * BB * DD + base + t*4;
    #pragma unroll
    for(int i = 0; i < 8; ++i) acc[i] += *(const f32x4*)(p + i*1024);
  }
  unsigned short* q = sumb + base + t*4;
  #pragma unroll
  for(int i = 0; i < 8; ++i){
    bf16x4 pk;
    #pragma unroll
    for(int j = 0; j < 4; ++j) pk[j] = (short)f2b(acc[i][j]);
    *(bf16x4*)(q + i*1024) = pk;
  }
}

// ---------------- K2: fused 4-layer MLP with LDS-staged weights ----------------
// 512 threads = 8 waves, 128 rows/block, grid 512. Weights loaded from global
// ONCE per block (vs once per wave before: 827 MB -> 114 MB weight traffic).
// LDS: [0,81920) AB weights (L0), reused [0,49152) for W1/W2/W3; [81920,+43008) act.
// Next layer's weights prefetched into registers during current layer's compute.
__global__ __launch_bounds__(512, 2) void fused_mlp(
    const float* __restrict__ signal,
    const unsigned short* __restrict__ sumb,
    const unsigned short* __restrict__ wAB,
    const unsigned short* __restrict__ w1p,
    const unsigned short* __restrict__ w2p,
    const unsigned short* __restrict__ w3p,
    const float* __restrict__ b0p, const float* __restrict__ b1p,
    const float* __restrict__ b2p, const float* __restrict__ b3p,
    float* __restrict__ out)
{
  __shared__ __align__(16) unsigned char ldsbuf[WAB_BYTES + ACT_BYTES];
  unsigned short* ldsAB = (unsigned short*)ldsbuf;               // 40960 el total
  unsigned short* ldsW  = (unsigned short*)ldsbuf;               // 24576 el (reuse)
  unsigned short* actB  = (unsigned short*)(ldsbuf + WAB_BYTES); // 8*16*168 el

  const int t    = threadIdx.x;       // 0..511
  const int lane = t & 63;
  const int wave = t >> 6;            // 0..7
  const int m    = lane & 15;
  const int quad = lane >> 4;
  const int rowBase = blockIdx.x * 128 + wave * 16;
  const int arow = rowBase + m;
  unsigned short* actW = actB + wave * 16 * SH;   // per-wave private 16x168 tile

  // zero act K-pad cols [144,160) (read by ki=4, never written by compute)
  for(int z = t; z < 8*16*16; z += 512){
    int wv = z >> 8, r = (z >> 4) & 15, c = z & 15;
    actB[(wv*16 + r)*SH + 144 + c] = 0;
  }

  // ---- issue A-fragment loads + AB staging loads ----
  bf16x8 sumf[4];
  #pragma unroll
  for(int ki = 0; ki < 4; ++ki)
    sumf[ki] = *(const bf16x8*)(sumb + (size_t)arow*DD + ki*32 + quad*8);

  f32x4 sl[8];
  {
    const float* srow = signal + (size_t)arow * DD;
    #pragma unroll
    for(int ki = 0; ki < 4; ++ki){
      sl[2*ki]   = *(const f32x4*)(srow + ki*32 + quad*8);
      sl[2*ki+1] = *(const f32x4*)(srow + ki*32 + quad*8 + 4);
    }
  }

  f32x4 rAB[10];
  {
    const f32x4* g = (const f32x4*)wAB;    // 5120 chunks of 16B
    #pragma unroll
    for(int c = 0; c < 10; ++c) rAB[c] = g[c*512 + t];
  }

  bf16x8 sigf[4];
  #pragma unroll
  for(int ki = 0; ki < 4; ++ki){
    bf16x8 p;
    #pragma unroll
    for(int j = 0; j < 4; ++j){ p[j] = (short)f2b(sl[2*ki][j]); p[4+j] = (short)f2b(sl[2*ki+1][j]); }
    sigf[ki] = p;
  }

  // publish AB
  {
    f32x4* l = (f32x4*)ldsAB;
    #pragma unroll
    for(int c = 0; c < 10; ++c) l[c*512 + t] = rAB[c];
  }
  __syncthreads();

  // prefetch W1 into regs
  f32x4 rW[6];
  {
    const f32x4* g = (const f32x4*)w1p;    // 3072 chunks
    #pragma unroll
    for(int c = 0; c < 6; ++c) rW[c] = g[c*512 + t];
  }

  // ---- layer 0: relu(sig @ w0s^T + sum @ w0r^T + b0) ----
  #pragma unroll
  for(int nt = 0; nt < 9; ++nt){
    f32x4 acc = {0.f,0.f,0.f,0.f};
    const int rb = nt*16 + m;
    #pragma unroll
    for(int ki = 0; ki < 4; ++ki){
      bf16x8 wf = *(const bf16x8*)(ldsAB + rb*SW + ki*32 + quad*8);
      acc = __builtin_amdgcn_mfma_f32_16x16x32_bf16(sigf[ki], wf, acc, 0, 0, 0);
    }
    #pragma unroll
    for(int ki = 0; ki < 4; ++ki){
      bf16x8 wf = *(const bf16x8*)(ldsAB + 20480 + rb*SW + ki*32 + quad*8);
      acc = __builtin_amdgcn_mfma_f32_16x16x32_bf16(sumf[ki], wf, acc, 0, 0, 0);
    }
    float bias = b0p[rb];
    #pragma unroll
    for(int r = 0; r < 4; ++r){
      float v = acc[r] + bias;
      v = v > 0.f ? v : 0.f;
      actW[(quad*4 + r)*SH + rb] = f2b(v);
    }
  }
  __syncthreads();                       // L0 done; AB region free

  // publish W1
  { f32x4* l = (f32x4*)ldsW;
    #pragma unroll
    for(int c = 0; c < 6; ++c) l[c*512 + t] = rW[c]; }
  __syncthreads();

  bf16x8 hf[5];

  // ---- layer 1 ----
  { const f32x4* g = (const f32x4*)w2p;  // prefetch W2
    #pragma unroll
    for(int c = 0; c < 6; ++c) rW[c] = g[c*512 + t]; }
  #pragma unroll
  for(int ki = 0; ki < 5; ++ki)
    hf[ki] = *(const bf16x8*)(actW + m*SH + ki*32 + quad*8);
  #pragma unroll
  for(int nt = 0; nt < 9; ++nt){
    f32x4 acc = {0.f,0.f,0.f,0.f};
    const int rb = nt*16 + m;
    #pragma unroll
    for(int ki = 0; ki < 5; ++ki){
      bf16x8 wf = *(const bf16x8*)(ldsW + rb*SH + ki*32 + quad*8);
      acc = __builtin_amdgcn_mfma_f32_16x16x32_bf16(hf[ki], wf, acc, 0, 0, 0);
    }
    float bias = b1p[rb];
    #pragma unroll
    for(int r = 0; r < 4; ++r){
      float v = acc[r] + bias;
      v = v > 0.f ? v : 0.f;
      actW[(quad*4 + r)*SH + rb] = f2b(v);
    }
  }
  __syncthreads();                       // L1 done; W region free

  { f32x4* l = (f32x4*)ldsW;             // publish W2
    #pragma unroll
    for(int c = 0; c < 6; ++c) l[c*512 + t] = rW[c]; }
  __syncthreads();

  // ---- layer 2 ----
  { const f32x4* g = (const f32x4*)w3p;  // prefetch W3
    #pragma unroll
    for(int c = 0; c < 6; ++c) rW[c] = g[c*512 + t]; }
  #pragma unroll
  for(int ki = 0; ki < 5; ++ki)
    hf[ki] = *(const bf16x8*)(actW + m*SH + ki*32 + quad*8);
  #pragma unroll
  for(int nt = 0; nt < 9; ++nt){
    f32x4 acc = {0.f,0.f,0.f,0.f};
    const int rb = nt*16 + m;
    #pragma unroll
    for(int ki = 0; ki < 5; ++ki){
      bf16x8 wf = *(const bf16x8*)(ldsW + rb*SH + ki*32 + quad*8);
      acc = __builtin_amdgcn_mfma_f32_16x16x32_bf16(hf[ki], wf, acc, 0, 0, 0);
    }
    float bias = b2p[rb];
    #pragma unroll
    for(int r = 0; r < 4; ++r){
      float v = acc[r] + bias;
      v = v > 0.f ? v : 0.f;
      actW[(quad*4 + r)*SH + rb] = f2b(v);
    }
  }
  __syncthreads();                       // L2 done

  { f32x4* l = (f32x4*)ldsW;             // publish W3
    #pragma unroll
    for(int c = 0; c < 6; ++c) l[c*512 + t] = rW[c]; }
  __syncthreads();

  // ---- layer 3 -> out (fp32) ----
  #pragma unroll
  for(int ki = 0; ki < 5; ++ki)
    hf[ki] = *(const bf16x8*)(actW + m*SH + ki*32 + quad*8);
  #pragma unroll
  for(int nt = 0; nt < 8; ++nt){
    f32x4 acc = {0.f,0.f,0.f,0.f};
    const int rb = nt*16 + m;
    #pragma unroll
    for(int ki = 0; ki < 5; ++ki){
      bf16x8 wf = *(const bf16x8*)(ldsW + rb*SH + ki*32 + quad*8);
      acc = __builtin_amdgcn_mfma_f32_16x16x32_bf16(hf[ki], wf, acc, 0, 0, 0);
    }
    float bias = b3p[rb];
    #pragma unroll
    for(int r = 0; r < 4; ++r){
      int grow = rowBase + quad*4 + r;
      out[(size_t)grow*DD + rb] = acc[r] + bias;
    }
  }
}

extern "C" void kernel_launch(void* const* d_in, const int* in_sizes, int n_in,
                              void* d_out, int out_size, void* d_ws, size_t ws_size,
                              hipStream_t stream){
  const float* signal = (const float*)d_in[0];
  const float* comps  = (const float*)d_in[1];
  const float* Wm = (const float*)d_in[2];
  const float* bm = (const float*)d_in[3];
  const float* Wu = (const float*)d_in[4];
  const float* bu = (const float*)d_in[5];
  const float* W0 = (const float*)d_in[6];
  const float* b0 = (const float*)d_in[7];
  const float* W1 = (const float*)d_in[8];
  const float* b1 = (const float*)d_in[9];
  const float* W2 = (const float*)d_in[10];
  const float* b2 = (const float*)d_in[11];
  const float* W3 = (const float*)d_in[12];
  const float* b3 = (const float*)d_in[13];

  char* ws = (char*)d_ws;
  float*          Wf   = (float*)(ws + 0);                 // 65536
  float*          bfv  = (float*)(ws + 65536);             // 512
  unsigned short* wAB  = (unsigned short*)(ws + 66048);    // 81920
  unsigned short* w1p  = (unsigned short*)(ws + 147968);   // 49152
  unsigned short* w2p  = (unsigned short*)(ws + 197120);   // 49152
  unsigned short* w3p  = (unsigned short*)(ws + 246272);   // 49152
  float*          b0p  = (float*)(ws + 295424);            // 576
  float*          b1p  = (float*)(ws + 296000);
  float*          b2p  = (float*)(ws + 296576);
  float*          b3p  = (float*)(ws + 297152);            // 512
  unsigned short* sumb = (unsigned short*)(ws + 297728);   // 16.8 MB

  hipLaunchKernelGGL(prepA, dim3(64), dim3(256), 0, stream, Wm, bm, Wu, bu, Wf, bfv);

  // items: 20480+20480+24576+24576+24576+144+144+144+128 = 115248 -> 451 blocks
  hipLaunchKernelGGL(prepB, dim3(451), dim3(256), 0, stream,
                     W0, b0, W1, b1, W2, b2, W3, b3, Wf, bfv,
                     wAB, w1p, w2p, w3p, b0p, b1p, b2p, b3p);

  hipLaunchKernelGGL(comp_sum, dim3(BB*DD/8192), dim3(256), 0, stream, comps, sumb);

  hipLaunchKernelGGL(fused_mlp, dim3(BB/128), dim3(512), 0, stream,
                     signal, sumb, wAB, w1p, w2p, w3p,
                     b0p, b1p, b2p, b3p, (float*)d_out);
}